// Round 7
// baseline (1869.151 us; speedup 1.0000x reference)
//
#include <hip/hip_runtime.h>

// Volume (B=2, C=1, D=192, H=192, W=192) fp32 in/out.
// R7 = R6 algorithm (verified absmax 0.0039) with an occupancy/latency attack:
//  - SINGLE-buffered LDS slab (8.4 KB, was 16.9 double-buffered) + second
//    LDS-only barrier after the reads. write->bar->read->bar is race-free.
//    R6 measured 27% occupancy ~= 3 blocks/CU = LDS-capped; halving LDS
//    doubles resident blocks even under a 64 KB effective pool.
//  - ZPT 8->12: 18 iters / 12 outputs (was 14/8) = -14% total iterations;
//    NBLK=1536 = 6 blocks/CU, one clean resident round.
//  - 2-deep strip prefetch (compile-time parity buffers): load-to-use
//    distance = 2 iterations to cover ~900cy HBM latency.
// Fused two-step kernel per launch: E1=erode(X), D1=dilate(E1),
// delta1=relu(X-D1), E2=erode(E1), D2=dilate(E2), delta2=relu(E1-D2),
// both skel updates; writes A_{j+2} and S only. Thread=x (coalesced),
// h2 pairs along y, LDS x-halo, z register pipeline (output z=p-3).

#define Dn 192
#define Hn 192
#define Wn 192
#define PLANE (Hn * Wn)
#define TOTAL_ELEMS (2 * Dn * Hn * Wn)
#define NYG (Hn / 4)         // 48 y-groups of 4 rows
#define ZPT 12               // z planes per thread
#define ZC (Dn / ZPT)        // 16 z-chunks
#define NBLK (NYG * ZC * 2)  // 1536 blocks = 6 per CU
#define NITER2 (ZPT + 6)     // 18 fused-2 pipeline iterations
#define NITER1 (ZPT + 4)     // 16 single-step pipeline iterations

// LDS-only barrier: orders ds ops across the workgroup without draining
// outstanding global (vmcnt) prefetches.
static __device__ __forceinline__ void lds_barrier() {
    asm volatile("s_waitcnt lgkmcnt(0)" ::: "memory");
    __builtin_amdgcn_s_barrier();
}

typedef _Float16 h2 __attribute__((ext_vector_type(2)));
typedef _Float16 h4 __attribute__((ext_vector_type(4)));

static __device__ __forceinline__ h2 h2min(h2 a, h2 b) { return __builtin_elementwise_min(a, b); }
static __device__ __forceinline__ h2 h2max(h2 a, h2 b) { return __builtin_elementwise_max(a, b); }
static __device__ __forceinline__ h2 h2min3(h2 a, h2 b, h2 c) { return h2min(h2min(a, b), c); }
static __device__ __forceinline__ h2 h2max3(h2 a, h2 b, h2 c) { return h2max(h2max(a, b), c); }
static __device__ __forceinline__ unsigned int u32(h2 v) { return __builtin_bit_cast(unsigned int, v); }
static __device__ __forceinline__ h2 h2c(unsigned int v) { return __builtin_bit_cast(h2, v); }

template <int CHUNK>
__device__ __forceinline__ int swizzle(int bid) {
    return (bid & 7) * CHUNK + (bid >> 3);
}

// ---------------- fused two-step kernel ----------------
template <bool FIRST>
__global__ __launch_bounds__(192, 5) void fused2_k(const void* __restrict__ X_,
                                                   const _Float16* Sin,
                                                   _Float16* Sout,
                                                   _Float16* __restrict__ Aout) {
    const float* Xf = (const float*)X_;
    const _Float16* Xh = (const _Float16*)X_;

    const int bid = swizzle<NBLK / 8>((int)blockIdx.x);
    const int gy = bid % NYG;
    const int t2 = bid / NYG;
    const int zc = t2 % ZC;
    const int b = t2 / ZC;
    const int x = threadIdx.x;         // 0..191, contiguous across lanes
    const int y0 = gy * 4;
    const int z0 = zc * ZPT;
    const int cbase = b * (Dn * PLANE) + y0 * Wn + x;

    // Clamped row offsets, rows y0-3 .. y0+6 (clamp = y-replicate boundary).
    int roff[10];
#pragma unroll
    for (int k = 0; k < 10; ++k) {
        int ry = y0 - 3 + k;
        ry = ry < 0 ? 0 : (ry > Hn - 1 ? Hn - 1 : ry);
        roff[k] = (ry - y0) * Wn;
    }

    // LDS (single-buffered): [x][0..3]=X slots -2..5, [4..6]=E1 trim -1..4,
    // [7..9]=E2 slots -1..4. Stride 11 (coprime 32 banks -> 2 lanes/bank).
    __shared__ unsigned int sh[192][11];
    const int xu = (x < Wn - 1) ? x + 1 : x;
    const int xd = (x > 0) ? x - 1 : x;

    // pipeline state (all zero-init; early-iteration consumers are gated)
    h2 aM1[4] = {}, aM2[4] = {}, hmM1[4] = {}, aUM1[4] = {}, aDM1[4] = {};
    h2 e1M1t[3] = {}, e1M2t[3] = {}, hm1M1[3] = {}, e1UM1[3] = {}, e1DM1[3] = {};
    h2 m1M1[2] = {}, m1M2[2] = {}, m1M3[2] = {};
    h2 m2M1[2] = {}, m2M2[2] = {};
    h2 xcM1[2] = {}, xcM2[2] = {}, xcM3[2] = {};
    h2 e1cM1[2] = {}, e1cM2[2] = {}, e2cM1[2] = {};
    h4 sP = {};

    // 2-deep strip prefetch, compile-time parity buffers (rule: static idx)
    _Float16 hP[2][10];
    float fP[2][10];
    auto issue = [&](int p, int buf) {
        int pz = p < 0 ? 0 : (p > Dn - 1 ? Dn - 1 : p);  // z-clamp (neutral)
        if (FIRST) {
            const float* pp = Xf + cbase + pz * PLANE;
#pragma unroll
            for (int k = 0; k < 10; ++k) fP[buf][k] = pp[roff[k]];
        } else {
            const _Float16* pp = Xh + cbase + pz * PLANE;
#pragma unroll
            for (int k = 0; k < 10; ++k) hP[buf][k] = pp[roff[k]];
        }
    };
    issue(z0 - 3, 0);
    issue(z0 - 2, 1);

#pragma unroll
    for (int i = 0; i < NITER2; ++i) {
        const int p = z0 - 3 + i;
        const int zo = p - 3;
        const int pb = i & 1;          // compile-time (full unroll)

        // ---- strip: 10 y-values [y0-3..y0+6] at (x, plane p)
        _Float16 s[10];
#pragma unroll
        for (int k = 0; k < 10; ++k) s[k] = FIRST ? (_Float16)fP[pb][k] : hP[pb][k];

        // refill this parity buffer for plane p+2 (consumed at iter i+2)
        if (i + 2 < NITER2) issue(p + 2, pb);

        // skel prefetch for NEXT iteration's output (plane p-2)
        h4 sN = {};
        if (!FIRST && i >= 5 && i + 1 < NITER2) {
            const _Float16* sp = Sin + cbase + (p - 2) * PLANE;
            sN.x = sp[0]; sN.y = sp[Wn]; sN.z = sp[2 * Wn]; sN.w = sp[3 * Wn];
        }

        // ---- per-plane X summaries
        h2 P[9];
#pragma unroll
        for (int k = 0; k < 9; ++k) { h2 t = {s[k], s[k + 1]}; P[k] = t; }
        h2 a0[4] = {P[1], P[3], P[5], P[7]};           // X slots -2..5
        h2 hm0[4];
#pragma unroll
        for (int j = 0; j < 4; ++j)
            hm0[j] = h2min3(P[2 * j], P[2 * j + 1], P[2 * j + 2]);  // y-min3
        h2 xc0[2] = {P[3], P[5]};                      // X center slots 0..3

        // ---- E1(p-1) slots -2..5 ; trim t slots -1..4 ; hm1(p-1) ; e1c(p-1)
        h2 e1[4] = {}, t[3] = {}, hm1_0[3] = {}, e1c0[2] = {};
        if (i >= 2) {
#pragma unroll
            for (int k = 0; k < 4; ++k)
                e1[k] = h2min3(h2min(hmM1[k], aM2[k]),
                               h2min(aUM1[k], aDM1[k]), a0[k]);
            if (gy == 0) { h2 v = {e1[1].x, e1[1].x}; e1[0] = v; }
            if (gy == NYG - 1) { h2 v = {e1[2].y, e1[2].y}; e1[3] = v; }
            t[0] = __builtin_shufflevector(e1[0], e1[1], 1, 2);
            t[1] = __builtin_shufflevector(e1[1], e1[2], 1, 2);
            t[2] = __builtin_shufflevector(e1[2], e1[3], 1, 2);
            hm1_0[0] = h2min3(e1[0], t[0], e1[1]);
            hm1_0[1] = h2min3(e1[1], t[1], e1[2]);
            hm1_0[2] = h2min3(e1[2], t[2], e1[3]);
            e1c0[0] = e1[1]; e1c0[1] = e1[2];
        }

        // ---- E2(p-2) slots -1..4 ; e2c(p-2)   (uses PREV-iter register state)
        h2 e2[3] = {}, e2c0[2] = {};
        if (i >= 4) {
#pragma unroll
            for (int j = 0; j < 3; ++j)
                e2[j] = h2min3(h2min(hm1M1[j], e1M2t[j]),
                               h2min(e1UM1[j], e1DM1[j]), t[j]);
            if (gy == 0) { h2 v = {e2[0].y, e2[0].y}; e2[0] = v; }
            if (gy == NYG - 1) { h2 v = {e2[2].x, e2[2].x}; e2[2] = v; }
            e2c0[0] = __builtin_shufflevector(e2[0], e2[1], 1, 2);
            e2c0[1] = __builtin_shufflevector(e2[1], e2[2], 1, 2);
        }

        // ---- LDS exchange: write -> bar -> read -> bar (single buffer)
#pragma unroll
        for (int k = 0; k < 4; ++k) sh[x][k] = u32(a0[k]);
        if (i >= 2) {
#pragma unroll
            for (int j = 0; j < 3; ++j) sh[x][4 + j] = u32(t[j]);
        }
        if (i >= 4) {
#pragma unroll
            for (int j = 0; j < 3; ++j) sh[x][7 + j] = u32(e2[j]);
        }
        lds_barrier();                 // writes visible to whole block
        h2 aU0[4], aD0[4];
#pragma unroll
        for (int k = 0; k < 4; ++k) {
            aU0[k] = h2c(sh[xu][k]);
            aD0[k] = h2c(sh[xd][k]);
        }
        h2 tU[3] = {}, tD[3] = {}, eUr[3] = {}, eDr[3] = {};
        if (i >= 2) {
#pragma unroll
            for (int j = 0; j < 3; ++j) {
                tU[j] = h2c(sh[xu][4 + j]);
                tD[j] = h2c(sh[xd][4 + j]);
            }
        }
        if (i >= 4) {
#pragma unroll
            for (int j = 0; j < 3; ++j) {
                eUr[j] = h2c(sh[xu][7 + j]);
                eDr[j] = h2c(sh[xd][7 + j]);
            }
        }
        lds_barrier();                 // all reads done -> buffer reusable

        // ---- m1(p-1) / m2(p-2): in-plane 3x3 max (register-only from here)
        h2 m1_0[2] = {}, m2_0[2] = {};
        if (i >= 2) {
            h2 vm0 = h2max3(t[0], tU[0], tD[0]);
            h2 vm1 = h2max3(t[1], tU[1], tD[1]);
            h2 vm2 = h2max3(t[2], tU[2], tD[2]);
            h2 mid01 = __builtin_shufflevector(vm0, vm1, 1, 2);
            h2 mid23 = __builtin_shufflevector(vm1, vm2, 1, 2);
            m1_0[0] = h2max3(vm0, mid01, vm1);   // m1(p-1) slots (0,1)
            m1_0[1] = h2max3(vm1, mid23, vm2);   // slots (2,3)
        }
        if (i >= 4) {
            h2 vm0 = h2max3(e2[0], eUr[0], eDr[0]);
            h2 vm1 = h2max3(e2[1], eUr[1], eDr[1]);
            h2 vm2 = h2max3(e2[2], eUr[2], eDr[2]);
            h2 mid01 = __builtin_shufflevector(vm0, vm1, 1, 2);
            h2 mid23 = __builtin_shufflevector(vm1, vm2, 1, 2);
            m2_0[0] = h2max3(vm0, mid01, vm1);   // m2(p-2) slots (0,1)
            m2_0[1] = h2max3(vm1, mid23, vm2);
        }

        // ---- output z = p-3
        if (i >= 6) {
            const int offo = cbase + zo * PLANE;
            const bool zlo = (zo == 0);
            const bool zhi = (zo == Dn - 1);
            // D1(z) from m1(z-1)=m1M3, m1(z)=m1M2, m1(z+1)=m1M1
            h2 d1a0 = zlo ? m1M2[0] : m1M3[0];
            h2 d1a1 = zlo ? m1M2[1] : m1M3[1];
            h2 d1c0 = zhi ? m1M2[0] : m1M1[0];
            h2 d1c1 = zhi ? m1M2[1] : m1M1[1];
            h2 D1_0 = h2max3(d1a0, m1M2[0], d1c0);
            h2 D1_1 = h2max3(d1a1, m1M2[1], d1c1);
            // D2(z) from m2(z-1)=m2M2, m2(z)=m2M1, m2(z+1)=m2_0
            h2 d2a0 = zlo ? m2M1[0] : m2M2[0];
            h2 d2a1 = zlo ? m2M1[1] : m2M2[1];
            h2 d2c0 = zhi ? m2M1[0] : m2_0[0];
            h2 d2c1 = zhi ? m2M1[1] : m2_0[1];
            h2 D2_0 = h2max3(d2a0, m2M1[0], d2c0);
            h2 D2_1 = h2max3(d2a1, m2M1[1], d2c1);

            float ex[4] = {(float)xcM3[0].x, (float)xcM3[0].y,
                           (float)xcM3[1].x, (float)xcM3[1].y};
            float e1v[4] = {(float)e1cM2[0].x, (float)e1cM2[0].y,
                            (float)e1cM2[1].x, (float)e1cM2[1].y};
            float d1[4] = {(float)D1_0.x, (float)D1_0.y, (float)D1_1.x, (float)D1_1.y};
            float d2[4] = {(float)D2_0.x, (float)D2_0.y, (float)D2_1.x, (float)D2_1.y};
            float sv[4] = {(float)sP.x, (float)sP.y, (float)sP.z, (float)sP.w};
#pragma unroll
            for (int q = 0; q < 4; ++q) {
                float de1 = fmaxf(ex[q] - d1[q], 0.f);
                float s1 = FIRST ? de1 : (sv[q] + fmaxf(de1 - sv[q] * de1, 0.f));
                float de2 = fmaxf(e1v[q] - d2[q], 0.f);
                sv[q] = s1 + fmaxf(de2 - s1 * de2, 0.f);
            }
            Sout[offo] = (_Float16)sv[0];
            Sout[offo + Wn] = (_Float16)sv[1];
            Sout[offo + 2 * Wn] = (_Float16)sv[2];
            Sout[offo + 3 * Wn] = (_Float16)sv[3];
            Aout[offo] = e2cM1[0].x;               // A_{j+2}[z] = E2 center
            Aout[offo + Wn] = e2cM1[0].y;
            Aout[offo + 2 * Wn] = e2cM1[1].x;
            Aout[offo + 3 * Wn] = e2cM1[1].y;
        }

        // ---- rotate pipeline state
#pragma unroll
        for (int k = 0; k < 4; ++k) {
            aM2[k] = aM1[k]; aM1[k] = a0[k];
            hmM1[k] = hm0[k]; aUM1[k] = aU0[k]; aDM1[k] = aD0[k];
        }
#pragma unroll
        for (int j = 0; j < 3; ++j) {
            e1M2t[j] = e1M1t[j]; e1M1t[j] = t[j];
            hm1M1[j] = hm1_0[j]; e1UM1[j] = tU[j]; e1DM1[j] = tD[j];
        }
        m1M3[0] = m1M2[0]; m1M3[1] = m1M2[1];
        m1M2[0] = m1M1[0]; m1M2[1] = m1M1[1];
        m1M1[0] = m1_0[0]; m1M1[1] = m1_0[1];
        m2M2[0] = m2M1[0]; m2M2[1] = m2M1[1];
        m2M1[0] = m2_0[0]; m2M1[1] = m2_0[1];
        xcM3[0] = xcM2[0]; xcM3[1] = xcM2[1];
        xcM2[0] = xcM1[0]; xcM2[1] = xcM1[1];
        xcM1[0] = xc0[0];  xcM1[1] = xc0[1];
        e1cM2[0] = e1cM1[0]; e1cM2[1] = e1cM1[1];
        e1cM1[0] = e1c0[0]; e1cM1[1] = e1c0[1];
        e2cM1[0] = e2c0[0]; e2cM1[1] = e2c0[1];
        sP = sN;
    }
}

// ---------------- single-step kernel, used for final step ----
template <bool FIRST, bool LAST>
__global__ __launch_bounds__(192, 5) void step_k(const void* __restrict__ X_,
                                                 const _Float16* Sin,
                                                 void* Sout_,
                                                 _Float16* __restrict__ Aout) {
    const float* Xf = (const float*)X_;
    const _Float16* Xh = (const _Float16*)X_;
    _Float16* Sh = (_Float16*)Sout_;
    float* Sf = (float*)Sout_;

    const int bid = swizzle<NBLK / 8>((int)blockIdx.x);
    const int gy = bid % NYG;
    const int t2 = bid / NYG;
    const int zc = t2 % ZC;
    const int b = t2 / ZC;
    const int x = threadIdx.x;
    const int y0 = gy * 4;
    const int z0 = zc * ZPT;
    const int cbase = b * (Dn * PLANE) + y0 * Wn + x;

    int roff[8];
#pragma unroll
    for (int k = 0; k < 8; ++k) {
        int ry = y0 - 2 + k;
        ry = ry < 0 ? 0 : (ry > Hn - 1 ? Hn - 1 : ry);
        roff[k] = (ry - y0) * Wn;
    }

    __shared__ unsigned int sh[192][7];
    const int xu = (x < Wn - 1) ? x + 1 : x;
    const int xd = (x > 0) ? x - 1 : x;

    h2 aM2[3] = {}, aM1[3] = {}, hmM1[3] = {}, aUM1[3] = {}, aDM1[3] = {};
    h2 xcM1[2] = {}, xcM2[2] = {}, e1cM1[2] = {}, mM1[2] = {}, mM2[2] = {};

    _Float16 hP[2][8];
    float fP[2][8];
    h4 sP = {};

    auto issue = [&](int p, int buf) {
        int pz = p < 0 ? 0 : (p > Dn - 1 ? Dn - 1 : p);
        if (FIRST) {
            const float* pp = Xf + cbase + pz * PLANE;
#pragma unroll
            for (int k = 0; k < 8; ++k) fP[buf][k] = pp[roff[k]];
        } else {
            const _Float16* pp = Xh + cbase + pz * PLANE;
#pragma unroll
            for (int k = 0; k < 8; ++k) hP[buf][k] = pp[roff[k]];
        }
    };
    issue(z0 - 2, 0);
    issue(z0 - 1, 1);

#pragma unroll
    for (int i = 0; i < NITER1; ++i) {
        const int p = z0 - 2 + i;
        const int zo = p - 2;
        const int pb = i & 1;

        _Float16 s[8];
#pragma unroll
        for (int k = 0; k < 8; ++k) s[k] = FIRST ? (_Float16)fP[pb][k] : hP[pb][k];

        if (i + 2 < NITER1) issue(p + 2, pb);

        h4 sN = {};
        if (!FIRST && i >= 3 && i + 1 < NITER1) {
            const _Float16* sp = Sin + cbase + (p - 1) * PLANE;
            sN.x = sp[0]; sN.y = sp[Wn]; sN.z = sp[2 * Wn]; sN.w = sp[3 * Wn];
        }

        h2 P[7];
#pragma unroll
        for (int k = 0; k < 7; ++k) { h2 t = {s[k], s[k + 1]}; P[k] = t; }
        h2 a0[3] = {P[1], P[3], P[5]};
        h2 hm0[3];
#pragma unroll
        for (int j = 0; j < 3; ++j)
            hm0[j] = h2min3(P[2 * j], P[2 * j + 1], P[2 * j + 2]);
        h2 xc0[2] = {P[2], P[4]};

        h2 e1[3] = {};
        if (i >= 2) {
#pragma unroll
            for (int k = 0; k < 3; ++k)
                e1[k] = h2min3(h2min(hmM1[k], aM2[k]),
                               h2min(aUM1[k], aDM1[k]), a0[k]);
            if (gy == 0)       e1[0] = __builtin_shufflevector(e1[0], e1[0], 1, 1);
            if (gy == NYG - 1) e1[2] = __builtin_shufflevector(e1[2], e1[2], 0, 0);
        }

        sh[x][0] = u32(a0[0]);
        sh[x][1] = u32(a0[1]);
        sh[x][2] = u32(a0[2]);
        if (i >= 2) {
            sh[x][3] = u32(e1[0]);
            sh[x][4] = u32(e1[1]);
            sh[x][5] = u32(e1[2]);
        }
        lds_barrier();
        h2 aU0[3] = {h2c(sh[xu][0]), h2c(sh[xu][1]), h2c(sh[xu][2])};
        h2 aD0[3] = {h2c(sh[xd][0]), h2c(sh[xd][1]), h2c(sh[xd][2])};
        h2 eU0 = {}, eU1 = {}, eU2 = {}, eD0 = {}, eD1 = {}, eD2 = {};
        if (i >= 2) {
            eU0 = h2c(sh[xu][3]); eU1 = h2c(sh[xu][4]); eU2 = h2c(sh[xu][5]);
            eD0 = h2c(sh[xd][3]); eD1 = h2c(sh[xd][4]); eD2 = h2c(sh[xd][5]);
        }
        lds_barrier();

        h2 m0[2] = {}, e1c0[2] = {};
        if (i >= 2) {
            h2 vm0 = h2max3(e1[0], eU0, eD0);
            h2 vm1 = h2max3(e1[1], eU1, eD1);
            h2 vm2 = h2max3(e1[2], eU2, eD2);
            h2 mid01 = __builtin_shufflevector(vm0, vm1, 1, 2);
            h2 mid23 = __builtin_shufflevector(vm1, vm2, 1, 2);
            m0[0] = h2max3(vm0, mid01, vm1);
            m0[1] = h2max3(vm1, mid23, vm2);
            e1c0[0] = __builtin_shufflevector(e1[0], e1[1], 1, 2);
            e1c0[1] = __builtin_shufflevector(e1[1], e1[2], 1, 2);
        }

        if (i >= 4) {
            const int offo = cbase + zo * PLANE;
            const bool zlo = (zo == 0);
            const bool zhi = (zo == Dn - 1);
            h2 mzA0 = zlo ? mM1[0] : mM2[0];
            h2 mzA1 = zlo ? mM1[1] : mM2[1];
            h2 mzC0 = zhi ? mM1[0] : m0[0];
            h2 mzC1 = zhi ? mM1[1] : m0[1];
            h2 d01 = h2max3(mzA0, mM1[0], mzC0);
            h2 d23 = h2max3(mzA1, mM1[1], mzC1);

            float ex0 = (float)xcM2[0].x, ex1 = (float)xcM2[0].y;
            float ex2 = (float)xcM2[1].x, ex3 = (float)xcM2[1].y;
            float de0 = fmaxf(ex0 - (float)d01.x, 0.f);
            float de1 = fmaxf(ex1 - (float)d01.y, 0.f);
            float de2 = fmaxf(ex2 - (float)d23.x, 0.f);
            float de3 = fmaxf(ex3 - (float)d23.y, 0.f);
            float s0, s1, s2, s3;
            if (FIRST) {
                s0 = de0; s1 = de1; s2 = de2; s3 = de3;
            } else {
                s0 = (float)sP.x; s1 = (float)sP.y;
                s2 = (float)sP.z; s3 = (float)sP.w;
                s0 += fmaxf(de0 - s0 * de0, 0.f);
                s1 += fmaxf(de1 - s1 * de1, 0.f);
                s2 += fmaxf(de2 - s2 * de2, 0.f);
                s3 += fmaxf(de3 - s3 * de3, 0.f);
            }
            if (LAST) {
                Sf[offo] = s0; Sf[offo + Wn] = s1;
                Sf[offo + 2 * Wn] = s2; Sf[offo + 3 * Wn] = s3;
            } else {
                Sh[offo] = (_Float16)s0;
                Sh[offo + Wn] = (_Float16)s1;
                Sh[offo + 2 * Wn] = (_Float16)s2;
                Sh[offo + 3 * Wn] = (_Float16)s3;
                Aout[offo] = e1cM1[0].x;
                Aout[offo + Wn] = e1cM1[0].y;
                Aout[offo + 2 * Wn] = e1cM1[1].x;
                Aout[offo + 3 * Wn] = e1cM1[1].y;
            }
        }

#pragma unroll
        for (int k = 0; k < 3; ++k) {
            aM2[k] = aM1[k]; aM1[k] = a0[k];
            hmM1[k] = hm0[k]; aUM1[k] = aU0[k]; aDM1[k] = aD0[k];
        }
        xcM2[0] = xcM1[0]; xcM2[1] = xcM1[1];
        xcM1[0] = xc0[0];  xcM1[1] = xc0[1];
        if (i >= 2) {
            mM2[0] = mM1[0]; mM2[1] = mM1[1];
            mM1[0] = m0[0];  mM1[1] = m0[1];
            e1cM1[0] = e1c0[0]; e1cM1[1] = e1c0[1];
        }
        sP = sN;
    }
}

extern "C" void kernel_launch(void* const* d_in, const int* in_sizes, int n_in,
                              void* d_out, int out_size, void* d_ws, size_t ws_size,
                              hipStream_t stream) {
    const float* img = (const float*)d_in[0];
    _Float16* B0 = (_Float16*)d_ws;
    _Float16* B1 = B0 + TOTAL_ELEMS;
    _Float16* S  = B1 + TOTAL_ELEMS;   // 3 x 28.3 MB workspace (fp16)

    // 41 opening steps: fused pair (0,1) from fp32 img, 19 fused pairs
    // (2,3)..(38,39), single final step 40 writing fp32 to d_out.
    fused2_k<true><<<NBLK, 192, 0, stream>>>(img, nullptr, S, B0);   // -> A_2
    _Float16* a = B0;
    _Float16* nb = B1;
    for (int j = 0; j < 19; ++j) {
        fused2_k<false><<<NBLK, 192, 0, stream>>>(a, S, S, nb);
        _Float16* t = a; a = nb; nb = t;                              // -> A_40
    }
    step_k<false, true><<<NBLK, 192, 0, stream>>>(a, S, d_out, nullptr);
}

// Round 8
// 954.381 us; speedup vs baseline: 1.9585x; 1.9585x over previous
//
#include <hip/hip_runtime.h>

// Volume (B=2, C=1, D=192, H=192, W=192) fp32 in/out.
// R8 = R6 (verified 930 us, absmax 0.0039) + ONE change: single-buffered LDS
// slab (8.4 KB, was 16.9 KB double-buffered) with write->bar->read->bar.
// R6 measured 27% occupancy = 3 blocks/CU = LDS-capped (64 KB effective pool
// / 16.9 KB). Halving LDS admits ~7 blocks/CU.
// R7's lesson (reverted here): 2-deep parity prefetch (hP[2][10], runtime-ish
// index through a lambda) was demoted to scratch -> VGPR 60->48, FETCH/WRITE
// 3x, 2x slower (guide rule #20). This version has NO dynamically-indexed
// register arrays: 1-deep prefetch hP[10], full static indexing.
//
// Fused two-step kernel per launch: E1=erode(X), D1=dilate(E1),
// delta1=relu(X-D1), E2=erode(E1), D2=dilate(E2), delta2=relu(E1-D2),
// both skel updates; writes A_{j+2} and S only. Thread=x (coalesced),
// h2 pairs along y, LDS x-halo, z register pipeline (output z=p-3).
// Packed-fp16 min/max (selections commute with monotone rounding);
// skel arithmetic fp32.

#define Dn 192
#define Hn 192
#define Wn 192
#define PLANE (Hn * Wn)
#define TOTAL_ELEMS (2 * Dn * Hn * Wn)
#define NYG (Hn / 4)         // 48 y-groups of 4 rows
#define ZPT 8                // z planes per thread
#define ZC (Dn / ZPT)        // 24 z-chunks
#define NBLK (NYG * ZC * 2)  // 2304 blocks
#define NITER2 (ZPT + 6)     // 14 fused-2 pipeline iterations
#define NITER1 (ZPT + 4)     // 12 single-step pipeline iterations

// LDS-only barrier: orders ds ops across the workgroup without draining
// outstanding global (vmcnt) prefetches.
static __device__ __forceinline__ void lds_barrier() {
    asm volatile("s_waitcnt lgkmcnt(0)" ::: "memory");
    __builtin_amdgcn_s_barrier();
}

typedef _Float16 h2 __attribute__((ext_vector_type(2)));
typedef _Float16 h4 __attribute__((ext_vector_type(4)));

static __device__ __forceinline__ h2 h2min(h2 a, h2 b) { return __builtin_elementwise_min(a, b); }
static __device__ __forceinline__ h2 h2max(h2 a, h2 b) { return __builtin_elementwise_max(a, b); }
static __device__ __forceinline__ h2 h2min3(h2 a, h2 b, h2 c) { return h2min(h2min(a, b), c); }
static __device__ __forceinline__ h2 h2max3(h2 a, h2 b, h2 c) { return h2max(h2max(a, b), c); }
static __device__ __forceinline__ unsigned int u32(h2 v) { return __builtin_bit_cast(unsigned int, v); }
static __device__ __forceinline__ h2 h2c(unsigned int v) { return __builtin_bit_cast(h2, v); }

template <int CHUNK>
__device__ __forceinline__ int swizzle(int bid) {
    return (bid & 7) * CHUNK + (bid >> 3);
}

// ---------------- fused two-step kernel ----------------
template <bool FIRST>
__global__ __launch_bounds__(192, 4) void fused2_k(const void* __restrict__ X_,
                                                   const _Float16* Sin,
                                                   _Float16* Sout,
                                                   _Float16* __restrict__ Aout) {
    const float* Xf = (const float*)X_;
    const _Float16* Xh = (const _Float16*)X_;

    const int bid = swizzle<NBLK / 8>((int)blockIdx.x);
    const int gy = bid % NYG;
    const int t2 = bid / NYG;
    const int zc = t2 % ZC;
    const int b = t2 / ZC;
    const int x = threadIdx.x;         // 0..191, contiguous across lanes
    const int y0 = gy * 4;
    const int z0 = zc * ZPT;
    const int cbase = b * (Dn * PLANE) + y0 * Wn + x;

    // Clamped row offsets, rows y0-3 .. y0+6 (clamp = y-replicate boundary).
    int roff[10];
#pragma unroll
    for (int k = 0; k < 10; ++k) {
        int ry = y0 - 3 + k;
        ry = ry < 0 ? 0 : (ry > Hn - 1 ? Hn - 1 : ry);
        roff[k] = (ry - y0) * Wn;
    }

    // LDS (single-buffered): [x][0..3]=X slots -2..5, [4..6]=E1 trim -1..4,
    // [7..9]=E2 slots -1..4. Stride 11 (coprime 32 banks -> 2 lanes/bank).
    __shared__ unsigned int sh[192][11];
    const int xu = (x < Wn - 1) ? x + 1 : x;
    const int xd = (x > 0) ? x - 1 : x;

    // pipeline state (all zero-init; early-iteration consumers are gated)
    h2 aM1[4] = {}, aM2[4] = {}, hmM1[4] = {}, aUM1[4] = {}, aDM1[4] = {};
    h2 e1M1t[3] = {}, e1M2t[3] = {}, hm1M1[3] = {}, e1UM1[3] = {}, e1DM1[3] = {};
    h2 m1M1[2] = {}, m1M2[2] = {}, m1M3[2] = {};
    h2 m2M1[2] = {}, m2M2[2] = {};
    h2 xcM1[2] = {}, xcM2[2] = {}, xcM3[2] = {};
    h2 e1cM1[2] = {}, e1cM2[2] = {}, e2cM1[2] = {};
    h4 sP = {};

    _Float16 hP[10];
    float fP[10];
    auto issue = [&](int p) {
        int pz = p < 0 ? 0 : (p > Dn - 1 ? Dn - 1 : p);  // z-clamp (neutral)
        if (FIRST) {
            const float* pp = Xf + cbase + pz * PLANE;
#pragma unroll
            for (int k = 0; k < 10; ++k) fP[k] = pp[roff[k]];
        } else {
            const _Float16* pp = Xh + cbase + pz * PLANE;
#pragma unroll
            for (int k = 0; k < 10; ++k) hP[k] = pp[roff[k]];
        }
    };
    issue(z0 - 3);

#pragma unroll
    for (int i = 0; i < NITER2; ++i) {
        const int p = z0 - 3 + i;
        const int zo = p - 3;

        // ---- strip: 10 y-values [y0-3..y0+6] at (x, plane p)
        _Float16 s[10];
#pragma unroll
        for (int k = 0; k < 10; ++k) s[k] = FIRST ? (_Float16)fP[k] : hP[k];

        // issue next plane's loads (consumed next iteration)
        if (i + 1 < NITER2) issue(p + 1);

        // skel prefetch for NEXT iteration's output (plane p-2)
        h4 sN = {};
        if (!FIRST && i >= 5 && i + 1 < NITER2) {
            const _Float16* sp = Sin + cbase + (p - 2) * PLANE;
            sN.x = sp[0]; sN.y = sp[Wn]; sN.z = sp[2 * Wn]; sN.w = sp[3 * Wn];
        }

        // ---- per-plane X summaries
        h2 P[9];
#pragma unroll
        for (int k = 0; k < 9; ++k) { h2 t = {s[k], s[k + 1]}; P[k] = t; }
        h2 a0[4] = {P[1], P[3], P[5], P[7]};           // X slots -2..5
        h2 hm0[4];
#pragma unroll
        for (int j = 0; j < 4; ++j)
            hm0[j] = h2min3(P[2 * j], P[2 * j + 1], P[2 * j + 2]);  // y-min3
        h2 xc0[2] = {P[3], P[5]};                      // X center slots 0..3

        // ---- E1(p-1) slots -2..5 ; trim t slots -1..4 ; hm1(p-1) ; e1c(p-1)
        h2 e1[4] = {}, t[3] = {}, hm1_0[3] = {}, e1c0[2] = {};
        if (i >= 2) {
#pragma unroll
            for (int k = 0; k < 4; ++k)
                e1[k] = h2min3(h2min(hmM1[k], aM2[k]),
                               h2min(aUM1[k], aDM1[k]), a0[k]);
            if (gy == 0) { h2 v = {e1[1].x, e1[1].x}; e1[0] = v; }
            if (gy == NYG - 1) { h2 v = {e1[2].y, e1[2].y}; e1[3] = v; }
            t[0] = __builtin_shufflevector(e1[0], e1[1], 1, 2);
            t[1] = __builtin_shufflevector(e1[1], e1[2], 1, 2);
            t[2] = __builtin_shufflevector(e1[2], e1[3], 1, 2);
            hm1_0[0] = h2min3(e1[0], t[0], e1[1]);
            hm1_0[1] = h2min3(e1[1], t[1], e1[2]);
            hm1_0[2] = h2min3(e1[2], t[2], e1[3]);
            e1c0[0] = e1[1]; e1c0[1] = e1[2];
        }

        // ---- E2(p-2) slots -1..4 ; e2c(p-2)   (uses PREV-iter register state)
        h2 e2[3] = {}, e2c0[2] = {};
        if (i >= 4) {
#pragma unroll
            for (int j = 0; j < 3; ++j)
                e2[j] = h2min3(h2min(hm1M1[j], e1M2t[j]),
                               h2min(e1UM1[j], e1DM1[j]), t[j]);
            if (gy == 0) { h2 v = {e2[0].y, e2[0].y}; e2[0] = v; }
            if (gy == NYG - 1) { h2 v = {e2[2].x, e2[2].x}; e2[2] = v; }
            e2c0[0] = __builtin_shufflevector(e2[0], e2[1], 1, 2);
            e2c0[1] = __builtin_shufflevector(e2[1], e2[2], 1, 2);
        }

        // ---- LDS exchange: write -> bar -> read -> bar (single buffer)
#pragma unroll
        for (int k = 0; k < 4; ++k) sh[x][k] = u32(a0[k]);
        if (i >= 2) {
#pragma unroll
            for (int j = 0; j < 3; ++j) sh[x][4 + j] = u32(t[j]);
        }
        if (i >= 4) {
#pragma unroll
            for (int j = 0; j < 3; ++j) sh[x][7 + j] = u32(e2[j]);
        }
        lds_barrier();                 // writes visible to whole block
        h2 aU0[4], aD0[4];
#pragma unroll
        for (int k = 0; k < 4; ++k) {
            aU0[k] = h2c(sh[xu][k]);
            aD0[k] = h2c(sh[xd][k]);
        }
        h2 tU[3] = {}, tD[3] = {}, eUr[3] = {}, eDr[3] = {};
        if (i >= 2) {
#pragma unroll
            for (int j = 0; j < 3; ++j) {
                tU[j] = h2c(sh[xu][4 + j]);
                tD[j] = h2c(sh[xd][4 + j]);
            }
        }
        if (i >= 4) {
#pragma unroll
            for (int j = 0; j < 3; ++j) {
                eUr[j] = h2c(sh[xu][7 + j]);
                eDr[j] = h2c(sh[xd][7 + j]);
            }
        }
        lds_barrier();                 // all reads done -> buffer reusable

        // ---- m1(p-1) / m2(p-2): in-plane 3x3 max (register-only from here)
        h2 m1_0[2] = {}, m2_0[2] = {};
        if (i >= 2) {
            h2 vm0 = h2max3(t[0], tU[0], tD[0]);
            h2 vm1 = h2max3(t[1], tU[1], tD[1]);
            h2 vm2 = h2max3(t[2], tU[2], tD[2]);
            h2 mid01 = __builtin_shufflevector(vm0, vm1, 1, 2);
            h2 mid23 = __builtin_shufflevector(vm1, vm2, 1, 2);
            m1_0[0] = h2max3(vm0, mid01, vm1);   // m1(p-1) slots (0,1)
            m1_0[1] = h2max3(vm1, mid23, vm2);   // slots (2,3)
        }
        if (i >= 4) {
            h2 vm0 = h2max3(e2[0], eUr[0], eDr[0]);
            h2 vm1 = h2max3(e2[1], eUr[1], eDr[1]);
            h2 vm2 = h2max3(e2[2], eUr[2], eDr[2]);
            h2 mid01 = __builtin_shufflevector(vm0, vm1, 1, 2);
            h2 mid23 = __builtin_shufflevector(vm1, vm2, 1, 2);
            m2_0[0] = h2max3(vm0, mid01, vm1);   // m2(p-2) slots (0,1)
            m2_0[1] = h2max3(vm1, mid23, vm2);
        }

        // ---- output z = p-3
        if (i >= 6) {
            const int offo = cbase + zo * PLANE;
            const bool zlo = (zo == 0);
            const bool zhi = (zo == Dn - 1);
            // D1(z) from m1(z-1)=m1M3, m1(z)=m1M2, m1(z+1)=m1M1
            h2 d1a0 = zlo ? m1M2[0] : m1M3[0];
            h2 d1a1 = zlo ? m1M2[1] : m1M3[1];
            h2 d1c0 = zhi ? m1M2[0] : m1M1[0];
            h2 d1c1 = zhi ? m1M2[1] : m1M1[1];
            h2 D1_0 = h2max3(d1a0, m1M2[0], d1c0);
            h2 D1_1 = h2max3(d1a1, m1M2[1], d1c1);
            // D2(z) from m2(z-1)=m2M2, m2(z)=m2M1, m2(z+1)=m2_0
            h2 d2a0 = zlo ? m2M1[0] : m2M2[0];
            h2 d2a1 = zlo ? m2M1[1] : m2M2[1];
            h2 d2c0 = zhi ? m2M1[0] : m2_0[0];
            h2 d2c1 = zhi ? m2M1[1] : m2_0[1];
            h2 D2_0 = h2max3(d2a0, m2M1[0], d2c0);
            h2 D2_1 = h2max3(d2a1, m2M1[1], d2c1);

            float ex[4] = {(float)xcM3[0].x, (float)xcM3[0].y,
                           (float)xcM3[1].x, (float)xcM3[1].y};
            float e1v[4] = {(float)e1cM2[0].x, (float)e1cM2[0].y,
                            (float)e1cM2[1].x, (float)e1cM2[1].y};
            float d1[4] = {(float)D1_0.x, (float)D1_0.y, (float)D1_1.x, (float)D1_1.y};
            float d2[4] = {(float)D2_0.x, (float)D2_0.y, (float)D2_1.x, (float)D2_1.y};
            float sv[4] = {(float)sP.x, (float)sP.y, (float)sP.z, (float)sP.w};
#pragma unroll
            for (int q = 0; q < 4; ++q) {
                float de1 = fmaxf(ex[q] - d1[q], 0.f);
                float s1 = FIRST ? de1 : (sv[q] + fmaxf(de1 - sv[q] * de1, 0.f));
                float de2 = fmaxf(e1v[q] - d2[q], 0.f);
                sv[q] = s1 + fmaxf(de2 - s1 * de2, 0.f);
            }
            Sout[offo] = (_Float16)sv[0];
            Sout[offo + Wn] = (_Float16)sv[1];
            Sout[offo + 2 * Wn] = (_Float16)sv[2];
            Sout[offo + 3 * Wn] = (_Float16)sv[3];
            Aout[offo] = e2cM1[0].x;               // A_{j+2}[z] = E2 center
            Aout[offo + Wn] = e2cM1[0].y;
            Aout[offo + 2 * Wn] = e2cM1[1].x;
            Aout[offo + 3 * Wn] = e2cM1[1].y;
        }

        // ---- rotate pipeline state
#pragma unroll
        for (int k = 0; k < 4; ++k) {
            aM2[k] = aM1[k]; aM1[k] = a0[k];
            hmM1[k] = hm0[k]; aUM1[k] = aU0[k]; aDM1[k] = aD0[k];
        }
#pragma unroll
        for (int j = 0; j < 3; ++j) {
            e1M2t[j] = e1M1t[j]; e1M1t[j] = t[j];
            hm1M1[j] = hm1_0[j]; e1UM1[j] = tU[j]; e1DM1[j] = tD[j];
        }
        m1M3[0] = m1M2[0]; m1M3[1] = m1M2[1];
        m1M2[0] = m1M1[0]; m1M2[1] = m1M1[1];
        m1M1[0] = m1_0[0]; m1M1[1] = m1_0[1];
        m2M2[0] = m2M1[0]; m2M2[1] = m2M1[1];
        m2M1[0] = m2_0[0]; m2M1[1] = m2_0[1];
        xcM3[0] = xcM2[0]; xcM3[1] = xcM2[1];
        xcM2[0] = xcM1[0]; xcM2[1] = xcM1[1];
        xcM1[0] = xc0[0];  xcM1[1] = xc0[1];
        e1cM2[0] = e1cM1[0]; e1cM2[1] = e1cM1[1];
        e1cM1[0] = e1c0[0]; e1cM1[1] = e1c0[1];
        e2cM1[0] = e2c0[0]; e2cM1[1] = e2c0[1];
        sP = sN;
    }
}

// ---------------- single-step kernel, used for final step ----
template <bool FIRST, bool LAST>
__global__ __launch_bounds__(192, 4) void step_k(const void* __restrict__ X_,
                                                 const _Float16* Sin,
                                                 void* Sout_,
                                                 _Float16* __restrict__ Aout) {
    const float* Xf = (const float*)X_;
    const _Float16* Xh = (const _Float16*)X_;
    _Float16* Sh = (_Float16*)Sout_;
    float* Sf = (float*)Sout_;

    const int bid = swizzle<NBLK / 8>((int)blockIdx.x);
    const int gy = bid % NYG;
    const int t2 = bid / NYG;
    const int zc = t2 % ZC;
    const int b = t2 / ZC;
    const int x = threadIdx.x;
    const int y0 = gy * 4;
    const int z0 = zc * ZPT;
    const int cbase = b * (Dn * PLANE) + y0 * Wn + x;

    int roff[8];
#pragma unroll
    for (int k = 0; k < 8; ++k) {
        int ry = y0 - 2 + k;
        ry = ry < 0 ? 0 : (ry > Hn - 1 ? Hn - 1 : ry);
        roff[k] = (ry - y0) * Wn;
    }

    __shared__ unsigned int sh[192][7];
    const int xu = (x < Wn - 1) ? x + 1 : x;
    const int xd = (x > 0) ? x - 1 : x;

    h2 aM2[3] = {}, aM1[3] = {}, hmM1[3] = {}, aUM1[3] = {}, aDM1[3] = {};
    h2 xcM1[2] = {}, xcM2[2] = {}, e1cM1[2] = {}, mM1[2] = {}, mM2[2] = {};

    _Float16 hP[8];
    float fP[8];
    h4 sP = {};

    auto issue = [&](int p) {
        int pz = p < 0 ? 0 : (p > Dn - 1 ? Dn - 1 : p);
        if (FIRST) {
            const float* pp = Xf + cbase + pz * PLANE;
#pragma unroll
            for (int k = 0; k < 8; ++k) fP[k] = pp[roff[k]];
        } else {
            const _Float16* pp = Xh + cbase + pz * PLANE;
#pragma unroll
            for (int k = 0; k < 8; ++k) hP[k] = pp[roff[k]];
        }
    };
    issue(z0 - 2);

#pragma unroll
    for (int i = 0; i < NITER1; ++i) {
        const int p = z0 - 2 + i;
        const int zo = p - 2;

        _Float16 s[8];
#pragma unroll
        for (int k = 0; k < 8; ++k) s[k] = FIRST ? (_Float16)fP[k] : hP[k];

        if (i + 1 < NITER1) issue(p + 1);

        h4 sN = {};
        if (!FIRST && i >= 3 && i + 1 < NITER1) {
            const _Float16* sp = Sin + cbase + (p - 1) * PLANE;
            sN.x = sp[0]; sN.y = sp[Wn]; sN.z = sp[2 * Wn]; sN.w = sp[3 * Wn];
        }

        h2 P[7];
#pragma unroll
        for (int k = 0; k < 7; ++k) { h2 t = {s[k], s[k + 1]}; P[k] = t; }
        h2 a0[3] = {P[1], P[3], P[5]};
        h2 hm0[3];
#pragma unroll
        for (int j = 0; j < 3; ++j)
            hm0[j] = h2min3(P[2 * j], P[2 * j + 1], P[2 * j + 2]);
        h2 xc0[2] = {P[2], P[4]};

        h2 e1[3] = {};
        if (i >= 2) {
#pragma unroll
            for (int k = 0; k < 3; ++k)
                e1[k] = h2min3(h2min(hmM1[k], aM2[k]),
                               h2min(aUM1[k], aDM1[k]), a0[k]);
            if (gy == 0)       e1[0] = __builtin_shufflevector(e1[0], e1[0], 1, 1);
            if (gy == NYG - 1) e1[2] = __builtin_shufflevector(e1[2], e1[2], 0, 0);
        }

        sh[x][0] = u32(a0[0]);
        sh[x][1] = u32(a0[1]);
        sh[x][2] = u32(a0[2]);
        if (i >= 2) {
            sh[x][3] = u32(e1[0]);
            sh[x][4] = u32(e1[1]);
            sh[x][5] = u32(e1[2]);
        }
        lds_barrier();
        h2 aU0[3] = {h2c(sh[xu][0]), h2c(sh[xu][1]), h2c(sh[xu][2])};
        h2 aD0[3] = {h2c(sh[xd][0]), h2c(sh[xd][1]), h2c(sh[xd][2])};
        h2 eU0 = {}, eU1 = {}, eU2 = {}, eD0 = {}, eD1 = {}, eD2 = {};
        if (i >= 2) {
            eU0 = h2c(sh[xu][3]); eU1 = h2c(sh[xu][4]); eU2 = h2c(sh[xu][5]);
            eD0 = h2c(sh[xd][3]); eD1 = h2c(sh[xd][4]); eD2 = h2c(sh[xd][5]);
        }
        lds_barrier();

        h2 m0[2] = {}, e1c0[2] = {};
        if (i >= 2) {
            h2 vm0 = h2max3(e1[0], eU0, eD0);
            h2 vm1 = h2max3(e1[1], eU1, eD1);
            h2 vm2 = h2max3(e1[2], eU2, eD2);
            h2 mid01 = __builtin_shufflevector(vm0, vm1, 1, 2);
            h2 mid23 = __builtin_shufflevector(vm1, vm2, 1, 2);
            m0[0] = h2max3(vm0, mid01, vm1);
            m0[1] = h2max3(vm1, mid23, vm2);
            e1c0[0] = __builtin_shufflevector(e1[0], e1[1], 1, 2);
            e1c0[1] = __builtin_shufflevector(e1[1], e1[2], 1, 2);
        }

        if (i >= 4) {
            const int offo = cbase + zo * PLANE;
            const bool zlo = (zo == 0);
            const bool zhi = (zo == Dn - 1);
            h2 mzA0 = zlo ? mM1[0] : mM2[0];
            h2 mzA1 = zlo ? mM1[1] : mM2[1];
            h2 mzC0 = zhi ? mM1[0] : m0[0];
            h2 mzC1 = zhi ? mM1[1] : m0[1];
            h2 d01 = h2max3(mzA0, mM1[0], mzC0);
            h2 d23 = h2max3(mzA1, mM1[1], mzC1);

            float ex0 = (float)xcM2[0].x, ex1 = (float)xcM2[0].y;
            float ex2 = (float)xcM2[1].x, ex3 = (float)xcM2[1].y;
            float de0 = fmaxf(ex0 - (float)d01.x, 0.f);
            float de1 = fmaxf(ex1 - (float)d01.y, 0.f);
            float de2 = fmaxf(ex2 - (float)d23.x, 0.f);
            float de3 = fmaxf(ex3 - (float)d23.y, 0.f);
            float s0, s1, s2, s3;
            if (FIRST) {
                s0 = de0; s1 = de1; s2 = de2; s3 = de3;
            } else {
                s0 = (float)sP.x; s1 = (float)sP.y;
                s2 = (float)sP.z; s3 = (float)sP.w;
                s0 += fmaxf(de0 - s0 * de0, 0.f);
                s1 += fmaxf(de1 - s1 * de1, 0.f);
                s2 += fmaxf(de2 - s2 * de2, 0.f);
                s3 += fmaxf(de3 - s3 * de3, 0.f);
            }
            if (LAST) {
                Sf[offo] = s0; Sf[offo + Wn] = s1;
                Sf[offo + 2 * Wn] = s2; Sf[offo + 3 * Wn] = s3;
            } else {
                Sh[offo] = (_Float16)s0;
                Sh[offo + Wn] = (_Float16)s1;
                Sh[offo + 2 * Wn] = (_Float16)s2;
                Sh[offo + 3 * Wn] = (_Float16)s3;
                Aout[offo] = e1cM1[0].x;
                Aout[offo + Wn] = e1cM1[0].y;
                Aout[offo + 2 * Wn] = e1cM1[1].x;
                Aout[offo + 3 * Wn] = e1cM1[1].y;
            }
        }

#pragma unroll
        for (int k = 0; k < 3; ++k) {
            aM2[k] = aM1[k]; aM1[k] = a0[k];
            hmM1[k] = hm0[k]; aUM1[k] = aU0[k]; aDM1[k] = aD0[k];
        }
        xcM2[0] = xcM1[0]; xcM2[1] = xcM1[1];
        xcM1[0] = xc0[0];  xcM1[1] = xc0[1];
        if (i >= 2) {
            mM2[0] = mM1[0]; mM2[1] = mM1[1];
            mM1[0] = m0[0];  mM1[1] = m0[1];
            e1cM1[0] = e1c0[0]; e1cM1[1] = e1c0[1];
        }
        sP = sN;
    }
}

extern "C" void kernel_launch(void* const* d_in, const int* in_sizes, int n_in,
                              void* d_out, int out_size, void* d_ws, size_t ws_size,
                              hipStream_t stream) {
    const float* img = (const float*)d_in[0];
    _Float16* B0 = (_Float16*)d_ws;
    _Float16* B1 = B0 + TOTAL_ELEMS;
    _Float16* S  = B1 + TOTAL_ELEMS;   // 3 x 28.3 MB workspace (fp16)

    // 41 opening steps: fused pair (0,1) from fp32 img, 19 fused pairs
    // (2,3)..(38,39), single final step 40 writing fp32 to d_out.
    fused2_k<true><<<NBLK, 192, 0, stream>>>(img, nullptr, S, B0);   // -> A_2
    _Float16* a = B0;
    _Float16* nb = B1;
    for (int j = 0; j < 19; ++j) {
        fused2_k<false><<<NBLK, 192, 0, stream>>>(a, S, S, nb);
        _Float16* t = a; a = nb; nb = t;                              // -> A_40
    }
    step_k<false, true><<<NBLK, 192, 0, stream>>>(a, S, d_out, nullptr);
}